// Round 13
// baseline (93.581 us; speedup 1.0000x reference)
//
#include <hip/hip_runtime.h>
#include <hip/hip_bf16.h>

// Problem constants (from reference):
// B=2, N=6, D=120, H=32, W=88, C=128, Z=1, HO=128, WO=128
#define HW_    2816
#define C_     128
#define BN_    12
#define SPAT_  16384
#define CELLS_ 32768
#define CPB_   128         // cells per range (512B/channel-row -> clean stores)
#define QBLK_  512         // persistent grid: exactly 2 blocks/CU -> no refill drift

// prep_k block-range dispatch
#define TF_BX     88                       // HW_/32
#define TF_BY     4                        // C_/32
#define TF_BLOCKS (TF_BX * TF_BY * BN_)    // 4224 transpose tiles
#define PG_BLOCKS 512                      // pregather: 512*256*8 = 1,048,576 slots
#define IV_BLOCKS 128                      // 128*256 = 32768 >= n_intervals

// round-to-nearest-even f32 -> bf16 (as uint in [0,0xffff]); finite values
__device__ __forceinline__ unsigned int f2bf_rne(float x) {
    const unsigned int u = __float_as_uint(x);
    return (u + 0x7fffu + ((u >> 16) & 1u)) >> 16;
}

// ---------------------------------------------------------------------------
// Fused prep (unchanged from r12):
//   [0, TF)      feat [BN,C,HW] f32 -> featT [BN,HW,C] bf16
//   [TF, +PG)    pair[i] = bf16(depth[rd[i]])<<16 | rf[i]  (rf < 33792 fits u16)
//   [.., +IV)    iv4[ivl] = {start, len, cell, 0}; map[cell]=ivl, gaps -> -1
// ---------------------------------------------------------------------------
__global__ __launch_bounds__(256) void prep_k(
        const float* __restrict__ feat, __hip_bfloat16* __restrict__ featT,
        const float* __restrict__ depth, const int* __restrict__ rd,
        const int* __restrict__ rf, unsigned int* __restrict__ pair, int n_points,
        const int* __restrict__ istart, const int* __restrict__ ilen,
        const int* __restrict__ rb, int4* __restrict__ iv4,
        int* __restrict__ map, int n_intervals) {
    __shared__ float tile[32][33];
    const int bid = blockIdx.x;
    const int tid = threadIdx.x;

    if (bid < TF_BLOCKS) {
        const int bn  = bid / (TF_BX * TF_BY);
        const int r   = bid - bn * (TF_BX * TF_BY);
        const int c0  = (r / TF_BX) * 32;
        const int hw0 = (r - (r / TF_BX) * TF_BX) * 32;
        const int x = tid & 31, y = tid >> 5;           // y in 0..7
        const float* src = feat + ((size_t)bn * C_ + c0) * HW_ + hw0;
        #pragma unroll
        for (int yy = y; yy < 32; yy += 8)
            tile[yy][x] = src[(size_t)yy * HW_ + x];     // coalesced along hw
        __syncthreads();
        __hip_bfloat16* dst = featT + ((size_t)bn * HW_ + hw0) * C_ + c0;
        #pragma unroll
        for (int yy = y; yy < 32; yy += 8)
            dst[(size_t)yy * C_ + x] = __float2bfloat16(tile[x][yy]);  // coalesced along c
    } else if (bid < TF_BLOCKS + PG_BLOCKS) {
        const int t = (bid - TF_BLOCKS) * 256 + tid;     // 0..131071
        const int S = PG_BLOCKS * 256;                   // 131072
        int idx[8], rfv[8];
        float v[8];
        #pragma unroll
        for (int u = 0; u < 8; ++u) {
            const int ii = t + u * S;
            const int cl = ii < n_points ? ii : t;       // clamp addr (u=0 valid)
            idx[u] = rd[cl];
            rfv[u] = rf[cl];
        }
        #pragma unroll
        for (int u = 0; u < 8; ++u) v[u] = depth[idx[u]];   // 8 gathers in flight
        #pragma unroll
        for (int u = 0; u < 8; ++u) {
            const int ii = t + u * S;
            if (ii < n_points)
                pair[ii] = (f2bf_rne(v[u]) << 16) | (unsigned)rfv[u];
        }
    } else {
        const int ivl = (bid - TF_BLOCKS - PG_BLOCKS) * 256 + tid;
        if (ivl < n_intervals) {
            const int s = istart[ivl];
            const int c = rb[s];
            iv4[ivl] = make_int4(s, ilen[ivl], c, 0);
            map[c] = ivl;
            const int cnext = (ivl + 1 < n_intervals) ? rb[istart[ivl + 1]] : CELLS_;
            for (int cc = c + 1; cc < cnext; ++cc) map[cc] = -1;   // gaps (~rare)
            if (ivl == 0) for (int cc = 0; cc < c; ++cc) map[cc] = -1;
        }
    }
}

// ---------------------------------------------------------------------------
// Main, persistent XCD-affine quarter-split, direct-to-out.
//  Grid = 512 blocks x 1024 thr, launch_bounds(1024,8) -> 2 blocks/CU ->
//  ALL blocks resident at t=0: initial round-robin bid%8 -> XCD holds for the
//  whole kernel (r12 lesson: refill drift killed parity on oversubscribed
//  grids). q = bid&3 == XCD&3 -> each XCD gathers only its 2.16 MB featT
//  quarter (lines disjoint per quarter) -> fits 4 MB L2 resident.
//  Each block: 2 ranges of 128 cells (bid>>2, +128). Wave = 8 cells SERIAL
//  (trip = sum of lens -> balanced; r12's max-of-16 imbalance fixed).
//  Per cell: 16 groups x 4 lanes over points (mod 16), 2 slots in flight;
//  lane owns 8 ch of the quarter (uint4 bf16x8); 4-shuffle fold; lanes 0..3
//  write LDS. LDS [128][33]: (33*cl+ch)%32=(cl+ch)%32 -> conflict-free
//  (r12's pad-36 was an 8-way conflict, 393K counted).
//  Store: 64 lanes x 4B = 256B contiguous per instr (r6-proven clean).
//  Empty cells -> LDS zeros; every out element written exactly once.
// ---------------------------------------------------------------------------
__global__ __launch_bounds__(1024, 8) void bevpool_cells_k(
        const unsigned int* __restrict__ pair,
        const uint4* __restrict__ featT,
        const int4* __restrict__ iv4,
        const int* __restrict__ map,
        float* __restrict__ out) {
    __shared__ float lds[CPB_][33];           // 16.9 KB
    const int bid  = blockIdx.x;
    const int q    = bid & 3;                 // channel quarter == XCD&3
    const int tid  = threadIdx.x;
    const int w    = tid >> 6;                // wave 0..15
    const int lane = tid & 63;
    const int g    = lane >> 2;               // point residue group 0..15
    const int sl   = lane & 3;                // channel chunk within quarter
    const size_t hoff = (size_t)(q * 4 + sl); // uint4 offset within 256B row

    #pragma unroll
    for (int rr = 0; rr < 2; ++rr) {
        const int range = (bid >> 2) + rr * (QBLK_ / 4);   // 0..255
        const int cell0 = range * CPB_;

        for (int i = tid; i < CPB_ * 33; i += 1024) (&lds[0][0])[i] = 0.f;
        __syncthreads();

        // wave w owns cells cell0 + w*8 .. +7, processed serially (balanced)
        for (int cc = 0; cc < 8; ++cc) {
            const int lc = w * 8 + cc;
            const int m  = map[cell0 + lc];
            if (m < 0) continue;                  // empty cell: LDS stays zero
            const int4 v    = iv4[m];
            const int start = v.x;
            const int end   = v.x + v.y;

            float acc[8] = {0.f, 0.f, 0.f, 0.f, 0.f, 0.f, 0.f, 0.f};
            for (int i = start + g; i < end; i += 32) {
                const int i1 = (i + 16 < end) ? i + 16 : i;    // clamp addr
                const unsigned p0 = pair[i];                   // 1 load/slot
                const unsigned p1 = pair[i1];
                const float d0 = __uint_as_float(p0 & 0xffff0000u);
                float d1 = __uint_as_float(p1 & 0xffff0000u);
                d1 = (i + 16 < end) ? d1 : 0.f;                // mul-by-0 tail
                const uint4 f0 = featT[(size_t)(p0 & 0xffffu) * 16 + hoff];
                const uint4 f1 = featT[(size_t)(p1 & 0xffffu) * 16 + hoff];
                acc[0] = fmaf(d0, __uint_as_float(f0.x << 16),         acc[0]);
                acc[1] = fmaf(d0, __uint_as_float(f0.x & 0xffff0000u), acc[1]);
                acc[2] = fmaf(d0, __uint_as_float(f0.y << 16),         acc[2]);
                acc[3] = fmaf(d0, __uint_as_float(f0.y & 0xffff0000u), acc[3]);
                acc[4] = fmaf(d0, __uint_as_float(f0.z << 16),         acc[4]);
                acc[5] = fmaf(d0, __uint_as_float(f0.z & 0xffff0000u), acc[5]);
                acc[6] = fmaf(d0, __uint_as_float(f0.w << 16),         acc[6]);
                acc[7] = fmaf(d0, __uint_as_float(f0.w & 0xffff0000u), acc[7]);
                acc[0] = fmaf(d1, __uint_as_float(f1.x << 16),         acc[0]);
                acc[1] = fmaf(d1, __uint_as_float(f1.x & 0xffff0000u), acc[1]);
                acc[2] = fmaf(d1, __uint_as_float(f1.y << 16),         acc[2]);
                acc[3] = fmaf(d1, __uint_as_float(f1.y & 0xffff0000u), acc[3]);
                acc[4] = fmaf(d1, __uint_as_float(f1.z << 16),         acc[4]);
                acc[5] = fmaf(d1, __uint_as_float(f1.z & 0xffff0000u), acc[5]);
                acc[6] = fmaf(d1, __uint_as_float(f1.w << 16),         acc[6]);
                acc[7] = fmaf(d1, __uint_as_float(f1.w & 0xffff0000u), acc[7]);
            }
            // fold 16 groups (stride-4 lanes): 32,16,8,4
            #pragma unroll
            for (int c = 0; c < 8; ++c) {
                acc[c] += __shfl_down(acc[c], 32);
                acc[c] += __shfl_down(acc[c], 16);
                acc[c] += __shfl_down(acc[c], 8);
                acc[c] += __shfl_down(acc[c], 4);
            }
            if (g == 0) {
                #pragma unroll
                for (int c = 0; c < 8; ++c) lds[lc][sl * 8 + c] = acc[c];
            }
        }
        __syncthreads();

        // cooperative store: 64 lanes x 4B = 256B contiguous per instr
        const int cl  = tid & 127;            // local cell
        const int chg = tid >> 7;             // 0..7
        const int b   = cell0 >> 14;
        const int sp0 = cell0 & (SPAT_ - 1);
        float* obase = out + ((size_t)b * C_ + q * 32) * SPAT_ + sp0;
        #pragma unroll
        for (int it = 0; it < 4; ++it) {
            const int ch = chg + 8 * it;      // 0..31 within the quarter
            obase[(size_t)ch * SPAT_ + cl] = lds[cl][ch];
        }
        __syncthreads();                      // before next range's LDS zero
    }
}

// ---------------------------------------------------------------------------
// Fallback (ws too small): original-layout reads, scattered stores.
// ---------------------------------------------------------------------------
__global__ __launch_bounds__(256) void bevpool_fallback_k(const float* __restrict__ depth,
                                                          const float* __restrict__ feat,
                                                          const int* __restrict__ rd_arr,
                                                          const int* __restrict__ rf_arr,
                                                          const int* __restrict__ rb,
                                                          const int* __restrict__ istart,
                                                          const int* __restrict__ ilen,
                                                          float* __restrict__ out,
                                                          int n_intervals) {
    const int wave = (int)((blockIdx.x * blockDim.x + threadIdx.x) >> 6);
    const int lane = threadIdx.x & 63;
    if (wave >= n_intervals) return;
    const int start = istart[wave];
    const int len   = ilen[wave];
    const int cell  = rb[start];
    float ax = 0.f, ay = 0.f;
    const int end = start + len;
    for (int i = start; i < end; ++i) {
        const int rfi = rf_arr[i];
        const int bn  = rfi / HW_;
        const int hw  = rfi - bn * HW_;
        const float d = depth[rd_arr[i]];
        const float* frow = feat + (size_t)bn * (C_ * HW_) + hw;
        ax = fmaf(d, frow[(size_t)(2 * lane)     * HW_], ax);
        ay = fmaf(d, frow[(size_t)(2 * lane + 1) * HW_], ay);
    }
    const int b  = cell >> 14;
    const int sp = cell & (SPAT_ - 1);
    float* o = out + (size_t)b * ((size_t)C_ * SPAT_) + sp;
    o[(size_t)(2 * lane)     * SPAT_] = ax;
    o[(size_t)(2 * lane + 1) * SPAT_] = ay;
}

extern "C" void kernel_launch(void* const* d_in, const int* in_sizes, int n_in,
                              void* d_out, int out_size, void* d_ws, size_t ws_size,
                              hipStream_t stream) {
    const float* depth  = (const float*)d_in[0];
    const float* feat   = (const float*)d_in[1];
    const int*   rd     = (const int*)d_in[2];
    const int*   rf     = (const int*)d_in[3];
    const int*   rb     = (const int*)d_in[4];
    const int*   istart = (const int*)d_in[5];
    const int*   ilen   = (const int*)d_in[6];
    float*       out    = (float*)d_out;
    const int n_intervals = in_sizes[5];
    const int n_points    = in_sizes[2];

    const size_t featT_bytes = (size_t)BN_ * HW_ * C_ * sizeof(__hip_bfloat16); // 8.65 MB
    const size_t pair_bytes  = ((size_t)n_points * sizeof(unsigned int) + 15) & ~(size_t)15;
    const size_t iv4_bytes   = (size_t)CELLS_ * sizeof(int4);                   // 0.52 MB
    const size_t map_bytes   = (size_t)CELLS_ * sizeof(int);                    // 0.13 MB

    if (ws_size >= featT_bytes + pair_bytes + iv4_bytes + map_bytes &&
        n_intervals <= CELLS_) {
        __hip_bfloat16* featT = (__hip_bfloat16*)d_ws;
        unsigned int*   pair  = (unsigned int*)((char*)d_ws + featT_bytes);
        int4*           iv4   = (int4*)((char*)d_ws + featT_bytes + pair_bytes);
        int*            map   = (int*)((char*)d_ws + featT_bytes + pair_bytes + iv4_bytes);

        const int prep_blocks = TF_BLOCKS + PG_BLOCKS + IV_BLOCKS;
        prep_k<<<prep_blocks, 256, 0, stream>>>(
            feat, featT, depth, rd, rf, pair, n_points,
            istart, ilen, rb, iv4, map, n_intervals);

        bevpool_cells_k<<<QBLK_, 1024, 0, stream>>>(
            pair, (const uint4*)featT, iv4, map, out);
    } else {
        hipMemsetAsync(out, 0, (size_t)out_size * sizeof(float), stream);
        const int blocks = (n_intervals + 3) / 4;
        bevpool_fallback_k<<<blocks, 256, 0, stream>>>(
            depth, feat, rd, rf, rb, istart, ilen, out, n_intervals);
    }
}

// Round 14
// 64.047 us; speedup vs baseline: 1.4611x; 1.4611x over previous
//
#include <hip/hip_runtime.h>
#include <hip/hip_bf16.h>

// Problem constants (from reference):
// B=2, N=6, D=120, H=32, W=88, C=128, Z=1, HO=128, WO=128
#define HW_    2816
#define C_     128
#define BN_    12
#define SPAT_  16384
#define CELLS_ 32768
#define CB_    64          // cells per main block (r11-proven best structure)

// prep_k block-range dispatch
#define TF_BX     88                       // HW_/32
#define TF_BY     4                        // C_/32
#define TF_BLOCKS (TF_BX * TF_BY * BN_)    // 4224 transpose tiles
#define PG_BLOCKS 512                      // pregather: 512*256*8 = 1,048,576 slots
#define IV_BLOCKS 128                      // 128*256 = 32768 >= n_intervals

// round-to-nearest-even f32 -> bf16 (as uint in [0,0xffff]); finite values
__device__ __forceinline__ unsigned int f2bf_rne(float x) {
    const unsigned int u = __float_as_uint(x);
    return (u + 0x7fffu + ((u >> 16) & 1u)) >> 16;
}

// ---------------------------------------------------------------------------
// Fused prep (r12/r13-proven):
//   [0, TF)      feat [BN,C,HW] f32 -> featT [BN,HW,C] bf16
//   [TF, +PG)    pair[i] = bf16(depth[rd[i]])<<16 | rf[i]  (rf < 33792 fits u16)
//   [.., +IV)    iv4[ivl] = {start, len, cell, 0}; map[cell]=ivl, gaps -> -1
// ---------------------------------------------------------------------------
__global__ __launch_bounds__(256) void prep_k(
        const float* __restrict__ feat, __hip_bfloat16* __restrict__ featT,
        const float* __restrict__ depth, const int* __restrict__ rd,
        const int* __restrict__ rf, unsigned int* __restrict__ pair, int n_points,
        const int* __restrict__ istart, const int* __restrict__ ilen,
        const int* __restrict__ rb, int4* __restrict__ iv4,
        int* __restrict__ map, int n_intervals) {
    __shared__ float tile[32][33];
    const int bid = blockIdx.x;
    const int tid = threadIdx.x;

    if (bid < TF_BLOCKS) {
        const int bn  = bid / (TF_BX * TF_BY);
        const int r   = bid - bn * (TF_BX * TF_BY);
        const int c0  = (r / TF_BX) * 32;
        const int hw0 = (r - (r / TF_BX) * TF_BX) * 32;
        const int x = tid & 31, y = tid >> 5;           // y in 0..7
        const float* src = feat + ((size_t)bn * C_ + c0) * HW_ + hw0;
        #pragma unroll
        for (int yy = y; yy < 32; yy += 8)
            tile[yy][x] = src[(size_t)yy * HW_ + x];     // coalesced along hw
        __syncthreads();
        __hip_bfloat16* dst = featT + ((size_t)bn * HW_ + hw0) * C_ + c0;
        #pragma unroll
        for (int yy = y; yy < 32; yy += 8)
            dst[(size_t)yy * C_ + x] = __float2bfloat16(tile[x][yy]);  // coalesced along c
    } else if (bid < TF_BLOCKS + PG_BLOCKS) {
        const int t = (bid - TF_BLOCKS) * 256 + tid;     // 0..131071
        const int S = PG_BLOCKS * 256;                   // 131072
        int idx[8], rfv[8];
        float v[8];
        #pragma unroll
        for (int u = 0; u < 8; ++u) {
            const int ii = t + u * S;
            const int cl = ii < n_points ? ii : t;       // clamp addr (u=0 valid)
            idx[u] = rd[cl];
            rfv[u] = rf[cl];
        }
        #pragma unroll
        for (int u = 0; u < 8; ++u) v[u] = depth[idx[u]];   // 8 gathers in flight
        #pragma unroll
        for (int u = 0; u < 8; ++u) {
            const int ii = t + u * S;
            if (ii < n_points)
                pair[ii] = (f2bf_rne(v[u]) << 16) | (unsigned)rfv[u];
        }
    } else {
        const int ivl = (bid - TF_BLOCKS - PG_BLOCKS) * 256 + tid;
        if (ivl < n_intervals) {
            const int s = istart[ivl];
            const int c = rb[s];
            iv4[ivl] = make_int4(s, ilen[ivl], c, 0);
            map[c] = ivl;
            const int cnext = (ivl + 1 < n_intervals) ? rb[istart[ivl + 1]] : CELLS_;
            for (int cc = c + 1; cc < cnext; ++cc) map[cc] = -1;   // gaps (~rare)
            if (ivl == 0) for (int cc = 0; cc < c; ++cc) map[cc] = -1;
        }
    }
}

#define FMA8(d, f)                                                   \
    acc[0] = fmaf(d, __uint_as_float((f).x << 16),         acc[0]);  \
    acc[1] = fmaf(d, __uint_as_float((f).x & 0xffff0000u), acc[1]);  \
    acc[2] = fmaf(d, __uint_as_float((f).y << 16),         acc[2]);  \
    acc[3] = fmaf(d, __uint_as_float((f).y & 0xffff0000u), acc[3]);  \
    acc[4] = fmaf(d, __uint_as_float((f).z << 16),         acc[4]);  \
    acc[5] = fmaf(d, __uint_as_float((f).z & 0xffff0000u), acc[5]);  \
    acc[6] = fmaf(d, __uint_as_float((f).w << 16),         acc[6]);  \
    acc[7] = fmaf(d, __uint_as_float((f).w & 0xffff0000u), acc[7]);

// FMA + rare-tail + fold + LDS store for one cell. Contains no prA/prB access
// so the caller controls the textual placement of prefetches.
__device__ __forceinline__ void cell_finish(
        const float d_[4], const uint4 f_[4], int i0, int e,
        const unsigned int* __restrict__ pair,
        const uint4* __restrict__ featT, size_t hoff,
        int grp, int sl, float* __restrict__ lds_row) {
    float acc[8] = {0.f, 0.f, 0.f, 0.f, 0.f, 0.f, 0.f, 0.f};
    #pragma unroll
    for (int u = 0; u < 4; ++u) { FMA8(d_[u], f_[u]); }
    // rare tail (len > 32): r11-proven inline body
    for (int i = i0 + 32; i < e; i += 32) {
        unsigned pr2[4];
        float d2[4];
        uint4 f2[4];
        #pragma unroll
        for (int u = 0; u < 4; ++u) {
            const int ii = i + 8 * u;
            pr2[u] = pair[(ii < e) ? ii : i];          // i valid (i < e)
        }
        #pragma unroll
        for (int u = 0; u < 4; ++u) d2[u] = __uint_as_float(pr2[u] & 0xffff0000u);
        #pragma unroll
        for (int u = 1; u < 4; ++u) d2[u] = (i + 8 * u < e) ? d2[u] : 0.f;
        #pragma unroll
        for (int u = 0; u < 4; ++u) f2[u] = featT[(size_t)(pr2[u] & 0xffffu) * 16 + hoff];
        #pragma unroll
        for (int u = 0; u < 4; ++u) { FMA8(d2[u], f2[u]); }
    }
    // fold 8 groups (8-lane stride): 32, 16, 8
    #pragma unroll
    for (int c = 0; c < 8; ++c) {
        acc[c] += __shfl_down(acc[c], 32);
        acc[c] += __shfl_down(acc[c], 16);
        acc[c] += __shfl_down(acc[c], 8);
    }
    if (grp == 0) {
        #pragma unroll
        for (int c = 0; c < 8; ++c) lds_row[sl * 8 + c] = acc[c];
    }
}

// ---------------------------------------------------------------------------
// Main, direct-to-out (r11 structure + cross-cell pair prefetch):
//  block = (64-cell range, channel-half); half = bid&1 (XCD parity).
//  16 waves x 4 cells each; metadata (map int4 + 4x iv4) prefetched up front
//  (r13 lesson: serial per-cell metadata chains cost 2.4x). Pair words for
//  cells q and q+1 prefetched before cell 0's compute; while cell q's FMAs
//  run, cell q+2's pairs are in flight (ping-pong prA/prB, static indexing).
//  Per cell: 8 groups x 8 lanes, 4 slots (stride 32) -> 4 feat rows +
//  4 pair loads per cell in flight, ~8-12 outstanding per wave steady-state.
//  LDS [64][65]: (65*cl+ch)%32 = (cl+ch)%32 -> conflict-free (r12's pad was
//  8-way). Store: 64 lanes x 4B = 256B contiguous per instr (r6-proven).
//  Empty cells -> LDS zeros; every out element written exactly once.
// ---------------------------------------------------------------------------
__global__ __launch_bounds__(1024, 8) void bevpool_cells_k(
        const unsigned int* __restrict__ pair,
        const uint4* __restrict__ featT,
        const int4* __restrict__ iv4,
        const int* __restrict__ map,
        float* __restrict__ out) {
    __shared__ float lds[CB_][65];            // 16.6 KB
    const int half  = blockIdx.x & 1;
    const int cb    = blockIdx.x >> 1;
    const int cell0 = cb * CB_;
    const int tid   = threadIdx.x;

    for (int i = tid; i < CB_ * 65; i += 1024) (&lds[0][0])[i] = 0.f;
    __syncthreads();

    const int widx = tid >> 6;       // 0..15
    const int lane = tid & 63;
    const int grp  = lane >> 3;      // 0..7: point residue class (mod 8)
    const int sl   = lane & 7;       // channel chunk within half
    const size_t hoff = (size_t)(half * 8 + sl);
    const int cl0  = widx * 4;       // this wave's first local cell

    const int4 m4 = *(const int4*)&map[cell0 + cl0];   // 4 interval ids
    const int m[4] = {m4.x, m4.y, m4.z, m4.w};
    int s[4], e[4];
    {
        const int4 v0 = iv4[m[0] < 0 ? 0 : m[0]];      // 4 independent loads
        const int4 v1 = iv4[m[1] < 0 ? 0 : m[1]];
        const int4 v2 = iv4[m[2] < 0 ? 0 : m[2]];
        const int4 v3 = iv4[m[3] < 0 ? 0 : m[3]];
        s[0] = v0.x; e[0] = v0.x + v0.y;
        s[1] = v1.x; e[1] = v1.x + v1.y;
        s[2] = v2.x; e[2] = v2.x + v2.y;
        s[3] = v3.x; e[3] = v3.x + v3.y;
    }

    // prefetch first-iteration pair words (4 slots, clamped to valid addrs)
#define PF(dst, qq)                                         \
    {                                                       \
        const int i0_ = s[qq] + grp;                        \
        _Pragma("unroll")                                   \
        for (int u = 0; u < 4; ++u) {                       \
            const int ii = i0_ + 8 * u;                     \
            dst[u] = pair[(ii < e[qq]) ? ii : s[qq]];       \
        }                                                   \
    }

#define CELL(qq, PR, PFNEXT)                                                  \
    {                                                                         \
        const int i0_ = s[qq] + grp;                                          \
        uint4 f_[4];                                                          \
        _Pragma("unroll")                                                     \
        for (int u = 0; u < 4; ++u)                                           \
            f_[u] = featT[(size_t)(PR[u] & 0xffffu) * 16 + hoff];             \
        float d_[4];                                                          \
        _Pragma("unroll")                                                     \
        for (int u = 0; u < 4; ++u) {                                         \
            const float dv = __uint_as_float(PR[u] & 0xffff0000u);            \
            d_[u] = (i0_ + 8 * u < e[qq]) ? dv : 0.f;                         \
        }                                                                     \
        PFNEXT                              /* next-next cell pairs in flight */ \
        if (m[qq] >= 0)                                                       \
            cell_finish(d_, f_, i0_, e[qq], pair, featT, hoff,                \
                        grp, sl, &lds[cl0 + qq][0]);                          \
    }

    unsigned prA[4], prB[4];
    PF(prA, 0)
    PF(prB, 1)
    CELL(0, prA, PF(prA, 2))
    CELL(1, prB, PF(prB, 3))
    CELL(2, prA, )
    CELL(3, prB, )
#undef CELL
#undef PF

    __syncthreads();

    // cooperative store: 64 lanes x 4B = 256B contiguous per instr (clean)
    const int cl  = tid & 63;
    const int chb = tid >> 6;                 // 0..15
    const int b   = cell0 >> 14;              // cell0 / SPAT_
    const int sp0 = cell0 & (SPAT_ - 1);
    float* obase = out + ((size_t)b * C_ + half * 64) * SPAT_ + sp0;
    #pragma unroll
    for (int it = 0; it < 4; ++it) {
        const int ch = chb + 16 * it;         // 0..63 within the half
        obase[(size_t)ch * SPAT_ + cl] = lds[cl][ch];
    }
}

// ---------------------------------------------------------------------------
// Fallback (ws too small): original-layout reads, scattered stores.
// ---------------------------------------------------------------------------
__global__ __launch_bounds__(256) void bevpool_fallback_k(const float* __restrict__ depth,
                                                          const float* __restrict__ feat,
                                                          const int* __restrict__ rd_arr,
                                                          const int* __restrict__ rf_arr,
                                                          const int* __restrict__ rb,
                                                          const int* __restrict__ istart,
                                                          const int* __restrict__ ilen,
                                                          float* __restrict__ out,
                                                          int n_intervals) {
    const int wave = (int)((blockIdx.x * blockDim.x + threadIdx.x) >> 6);
    const int lane = threadIdx.x & 63;
    if (wave >= n_intervals) return;
    const int start = istart[wave];
    const int len   = ilen[wave];
    const int cell  = rb[start];
    float ax = 0.f, ay = 0.f;
    const int end = start + len;
    for (int i = start; i < end; ++i) {
        const int rfi = rf_arr[i];
        const int bn  = rfi / HW_;
        const int hw  = rfi - bn * HW_;
        const float d = depth[rd_arr[i]];
        const float* frow = feat + (size_t)bn * (C_ * HW_) + hw;
        ax = fmaf(d, frow[(size_t)(2 * lane)     * HW_], ax);
        ay = fmaf(d, frow[(size_t)(2 * lane + 1) * HW_], ay);
    }
    const int b  = cell >> 14;
    const int sp = cell & (SPAT_ - 1);
    float* o = out + (size_t)b * ((size_t)C_ * SPAT_) + sp;
    o[(size_t)(2 * lane)     * SPAT_] = ax;
    o[(size_t)(2 * lane + 1) * SPAT_] = ay;
}

extern "C" void kernel_launch(void* const* d_in, const int* in_sizes, int n_in,
                              void* d_out, int out_size, void* d_ws, size_t ws_size,
                              hipStream_t stream) {
    const float* depth  = (const float*)d_in[0];
    const float* feat   = (const float*)d_in[1];
    const int*   rd     = (const int*)d_in[2];
    const int*   rf     = (const int*)d_in[3];
    const int*   rb     = (const int*)d_in[4];
    const int*   istart = (const int*)d_in[5];
    const int*   ilen   = (const int*)d_in[6];
    float*       out    = (float*)d_out;
    const int n_intervals = in_sizes[5];
    const int n_points    = in_sizes[2];

    const size_t featT_bytes = (size_t)BN_ * HW_ * C_ * sizeof(__hip_bfloat16); // 8.65 MB
    const size_t pair_bytes  = ((size_t)n_points * sizeof(unsigned int) + 15) & ~(size_t)15;
    const size_t iv4_bytes   = (size_t)CELLS_ * sizeof(int4);                   // 0.52 MB
    const size_t map_bytes   = (size_t)CELLS_ * sizeof(int);                    // 0.13 MB

    if (ws_size >= featT_bytes + pair_bytes + iv4_bytes + map_bytes &&
        n_intervals <= CELLS_) {
        __hip_bfloat16* featT = (__hip_bfloat16*)d_ws;
        unsigned int*   pair  = (unsigned int*)((char*)d_ws + featT_bytes);
        int4*           iv4   = (int4*)((char*)d_ws + featT_bytes + pair_bytes);
        int*            map   = (int*)((char*)d_ws + featT_bytes + pair_bytes + iv4_bytes);

        const int prep_blocks = TF_BLOCKS + PG_BLOCKS + IV_BLOCKS;
        prep_k<<<prep_blocks, 256, 0, stream>>>(
            feat, featT, depth, rd, rf, pair, n_points,
            istart, ilen, rb, iv4, map, n_intervals);

        bevpool_cells_k<<<(CELLS_ / CB_) * 2, 1024, 0, stream>>>(
            pair, (const uint4*)featT, iv4, map, out);
    } else {
        hipMemsetAsync(out, 0, (size_t)out_size * sizeof(float), stream);
        const int blocks = (n_intervals + 3) / 4;
        bevpool_fallback_k<<<blocks, 256, 0, stream>>>(
            depth, feat, rd, rf, rb, istart, ilen, out, n_intervals);
    }
}

// Round 15
// 58.993 us; speedup vs baseline: 1.5863x; 1.0857x over previous
//
#include <hip/hip_runtime.h>
#include <hip/hip_bf16.h>

// Problem constants (from reference):
// B=2, N=6, D=120, H=32, W=88, C=128, Z=1, HO=128, WO=128
#define HW_    2816
#define C_     128
#define BN_    12
#define SPAT_  16384
#define CELLS_ 32768
#define CB_    64          // cells per main block (64 lanes x 4B = 256B clean stores)

// prep_k block-range dispatch
#define TF_BX     88                       // HW_/32
#define TF_BY     4                        // C_/32
#define TF_BLOCKS (TF_BX * TF_BY * BN_)    // 4224 transpose tiles
#define PG_BLOCKS 1024                     // pregather/pack
#define IV_BLOCKS 128                      // 128*256 = 32768 >= n_intervals

// round-to-nearest-even f32 -> bf16 (as uint in [0,0xffff]); finite values
__device__ __forceinline__ unsigned int f2bf_rne(float x) {
    const unsigned int u = __float_as_uint(x);
    return (u + 0x7fffu + ((u >> 16) & 1u)) >> 16;
}

// ---------------------------------------------------------------------------
// Fused prep:
//   [0, TF)      feat [BN,C,HW] f32 -> featT [BN,HW,C] bf16
//   [TF, +PG)    pair[i] = bf16(depth[rd[i]])<<16 | rf[i]   (rf < 33792 fits u16)
//   [.., +IV)    iv4[ivl] = {start, len, cell, 0};  map[cell] = ivl, and each
//                thread fills the gap (cell, next_cell) with -1 -> race-free
//                full cell->interval map (rb sorted).
// ---------------------------------------------------------------------------
__global__ __launch_bounds__(256) void prep_k(
        const float* __restrict__ feat, __hip_bfloat16* __restrict__ featT,
        const float* __restrict__ depth, const int* __restrict__ rd,
        const int* __restrict__ rf, unsigned int* __restrict__ pair, int n_points,
        const int* __restrict__ istart, const int* __restrict__ ilen,
        const int* __restrict__ rb, int4* __restrict__ iv4,
        int* __restrict__ map, int n_intervals) {
    __shared__ float tile[32][33];
    const int bid = blockIdx.x;
    const int tid = threadIdx.x;

    if (bid < TF_BLOCKS) {
        const int bn  = bid / (TF_BX * TF_BY);
        const int r   = bid - bn * (TF_BX * TF_BY);
        const int c0  = (r / TF_BX) * 32;
        const int hw0 = (r - (r / TF_BX) * TF_BX) * 32;
        const int x = tid & 31, y = tid >> 5;           // y in 0..7
        const float* src = feat + ((size_t)bn * C_ + c0) * HW_ + hw0;
        #pragma unroll
        for (int yy = y; yy < 32; yy += 8)
            tile[yy][x] = src[(size_t)yy * HW_ + x];     // coalesced along hw
        __syncthreads();
        __hip_bfloat16* dst = featT + ((size_t)bn * HW_ + hw0) * C_ + c0;
        #pragma unroll
        for (int yy = y; yy < 32; yy += 8)
            dst[(size_t)yy * C_ + x] = __float2bfloat16(tile[x][yy]);  // coalesced along c
    } else if (bid < TF_BLOCKS + PG_BLOCKS) {
        const int t = (bid - TF_BLOCKS) * 256 + tid;
        const int stride = PG_BLOCKS * 256;
        for (int base = t; base < n_points; base += 4 * stride) {
            int ii[4], idx[4], rfv[4];
            float v[4];
            #pragma unroll
            for (int u = 0; u < 4; ++u) {
                ii[u] = base + u * stride;
                const int cl = ii[u] < n_points ? ii[u] : base;  // clamp addr
                idx[u] = rd[cl];
                rfv[u] = rf[cl];
            }
            #pragma unroll
            for (int u = 0; u < 4; ++u) v[u] = depth[idx[u]];    // 4 gathers in flight
            #pragma unroll
            for (int u = 0; u < 4; ++u)
                if (ii[u] < n_points)
                    pair[ii[u]] = (f2bf_rne(v[u]) << 16) | (unsigned)rfv[u];
        }
    } else {
        const int ivl = (bid - TF_BLOCKS - PG_BLOCKS) * 256 + tid;
        if (ivl < n_intervals) {
            const int s = istart[ivl];
            const int c = rb[s];
            iv4[ivl] = make_int4(s, ilen[ivl], c, 0);
            map[c] = ivl;
            const int cnext = (ivl + 1 < n_intervals) ? rb[istart[ivl + 1]] : CELLS_;
            for (int cc = c + 1; cc < cnext; ++cc) map[cc] = -1;   // gaps (~none)
            if (ivl == 0) for (int cc = 0; cc < c; ++cc) map[cc] = -1;
        }
    }
}

// ---------------------------------------------------------------------------
// Main, direct-to-out: block = (64-cell range, channel-half). blockIdx.x&1 ->
// XCD parity, so each XCD gathers only its 4.33 MB featT half (r7-proven).
// 16 waves x 4 cells; per interval the r10-proven gather loop: ONE pair load
// per slot (bf16 d | rf16) feeding the featT gather, 4 slots in flight;
// 8 groups x 8 lanes, lane owns 8 channels of the half. Results staged f32
// in LDS [64][68]; cooperative store writes each channel row as 64 lanes x
// 4B = 256B FULLY CONTIGUOUS per instruction (r6-proven clean granularity;
// 64B segments are 17x amplified, r5). Every out element written exactly
// once (empty cells -> LDS zeros) => no zero pass, no cellbuf, no transpose.
// ---------------------------------------------------------------------------
__global__ __launch_bounds__(1024, 4) void bevpool_cells_k(
        const unsigned int* __restrict__ pair,
        const uint4* __restrict__ featT,
        const int4* __restrict__ iv4,
        const int* __restrict__ map,
        float* __restrict__ out) {
    __shared__ float lds[CB_][68];   // pad 68: rows 16B-aligned; minor read conflict ok
    const int half  = blockIdx.x & 1;
    const int cb    = blockIdx.x >> 1;        // 0..511
    const int cell0 = cb * CB_;
    const int tid   = threadIdx.x;

    #pragma unroll
    for (int i = tid; i < CB_ * 68; i += 1024) (&lds[0][0])[i] = 0.f;
    __syncthreads();

    const int widx = tid >> 6;       // 0..15
    const int lane = tid & 63;
    const int grp  = lane >> 3;      // 0..7: point residue class (mod 8)
    const int sl   = lane & 7;       // channel chunk within half
    const size_t hoff = (size_t)(half * 8 + sl);
    const int cl0  = widx * 4;       // this wave's first local cell

    const int4 m4 = *(const int4*)&map[cell0 + cl0];   // 4 interval ids (16B aligned)
    const int m[4] = {m4.x, m4.y, m4.z, m4.w};
    int4 vq[4];
    #pragma unroll
    for (int q = 0; q < 4; ++q) vq[q] = iv4[m[q] < 0 ? 0 : m[q]];  // 4 indep loads

    #pragma unroll
    for (int q = 0; q < 4; ++q) {
        if (m[q] < 0) continue;                    // empty cell: LDS stays zero
        const int start = vq[q].x;
        const int end   = vq[q].x + vq[q].y;

        float acc[8] = {0.f, 0.f, 0.f, 0.f, 0.f, 0.f, 0.f, 0.f};
        for (int i = start + grp; i < end; i += 32) {
            int cl_[4];
            unsigned pr_[4];
            float d_[4];
            uint4 f_[4];
            #pragma unroll
            for (int u = 0; u < 4; ++u) {
                const int ii = i + 8 * u;
                cl_[u] = (ii < end) ? ii : i;      // clamp to valid address
            }
            #pragma unroll
            for (int u = 0; u < 4; ++u) pr_[u] = pair[cl_[u]];  // 1 stream load/slot
            #pragma unroll
            for (int u = 0; u < 4; ++u) d_[u] = __uint_as_float(pr_[u] & 0xffff0000u);
            #pragma unroll
            for (int u = 1; u < 4; ++u) d_[u] = (i + 8 * u < end) ? d_[u] : 0.f;
            #pragma unroll
            for (int u = 0; u < 4; ++u)
                f_[u] = featT[(size_t)(pr_[u] & 0xffffu) * 16 + hoff];
            #pragma unroll
            for (int u = 0; u < 4; ++u) {
                const float d = d_[u];
                acc[0] = fmaf(d, __uint_as_float(f_[u].x << 16),         acc[0]);
                acc[1] = fmaf(d, __uint_as_float(f_[u].x & 0xffff0000u), acc[1]);
                acc[2] = fmaf(d, __uint_as_float(f_[u].y << 16),         acc[2]);
                acc[3] = fmaf(d, __uint_as_float(f_[u].y & 0xffff0000u), acc[3]);
                acc[4] = fmaf(d, __uint_as_float(f_[u].z << 16),         acc[4]);
                acc[5] = fmaf(d, __uint_as_float(f_[u].z & 0xffff0000u), acc[5]);
                acc[6] = fmaf(d, __uint_as_float(f_[u].w << 16),         acc[6]);
                acc[7] = fmaf(d, __uint_as_float(f_[u].w & 0xffff0000u), acc[7]);
            }
        }
        #pragma unroll
        for (int c = 0; c < 8; ++c) {
            acc[c] += __shfl_down(acc[c], 32);
            acc[c] += __shfl_down(acc[c], 16);
            acc[c] += __shfl_down(acc[c], 8);
        }
        if (grp == 0) {
            #pragma unroll
            for (int c = 0; c < 8; ++c) lds[cl0 + q][sl * 8 + c] = acc[c];
        }
    }
    __syncthreads();

    // cooperative store: wave instr = 64 lanes x 4B = 256B contiguous (clean)
    const int cl  = tid & 63;
    const int chb = tid >> 6;                 // 0..15
    const int b   = cell0 >> 14;              // cell0 / SPAT_
    const int sp0 = cell0 & (SPAT_ - 1);
    float* obase = out + ((size_t)b * C_ + half * 64) * SPAT_ + sp0;
    #pragma unroll
    for (int it = 0; it < 4; ++it) {
        const int ch = chb + 16 * it;         // 0..63 within the half
        obase[(size_t)ch * SPAT_ + cl] = lds[cl][ch];
    }
}

// ---------------------------------------------------------------------------
// Fallback (ws too small): original-layout reads, scattered stores.
// ---------------------------------------------------------------------------
__global__ __launch_bounds__(256) void bevpool_fallback_k(const float* __restrict__ depth,
                                                          const float* __restrict__ feat,
                                                          const int* __restrict__ rd_arr,
                                                          const int* __restrict__ rf_arr,
                                                          const int* __restrict__ rb,
                                                          const int* __restrict__ istart,
                                                          const int* __restrict__ ilen,
                                                          float* __restrict__ out,
                                                          int n_intervals) {
    const int wave = (int)((blockIdx.x * blockDim.x + threadIdx.x) >> 6);
    const int lane = threadIdx.x & 63;
    if (wave >= n_intervals) return;
    const int start = istart[wave];
    const int len   = ilen[wave];
    const int cell  = rb[start];
    float ax = 0.f, ay = 0.f;
    const int end = start + len;
    for (int i = start; i < end; ++i) {
        const int rfi = rf_arr[i];
        const int bn  = rfi / HW_;
        const int hw  = rfi - bn * HW_;
        const float d = depth[rd_arr[i]];
        const float* frow = feat + (size_t)bn * (C_ * HW_) + hw;
        ax = fmaf(d, frow[(size_t)(2 * lane)     * HW_], ax);
        ay = fmaf(d, frow[(size_t)(2 * lane + 1) * HW_], ay);
    }
    const int b  = cell >> 14;
    const int sp = cell & (SPAT_ - 1);
    float* o = out + (size_t)b * ((size_t)C_ * SPAT_) + sp;
    o[(size_t)(2 * lane)     * SPAT_] = ax;
    o[(size_t)(2 * lane + 1) * SPAT_] = ay;
}

extern "C" void kernel_launch(void* const* d_in, const int* in_sizes, int n_in,
                              void* d_out, int out_size, void* d_ws, size_t ws_size,
                              hipStream_t stream) {
    const float* depth  = (const float*)d_in[0];
    const float* feat   = (const float*)d_in[1];
    const int*   rd     = (const int*)d_in[2];
    const int*   rf     = (const int*)d_in[3];
    const int*   rb     = (const int*)d_in[4];
    const int*   istart = (const int*)d_in[5];
    const int*   ilen   = (const int*)d_in[6];
    float*       out    = (float*)d_out;
    const int n_intervals = in_sizes[5];
    const int n_points    = in_sizes[2];

    const size_t featT_bytes = (size_t)BN_ * HW_ * C_ * sizeof(__hip_bfloat16); // 8.65 MB
    const size_t pair_bytes  = ((size_t)n_points * sizeof(unsigned int) + 15) & ~(size_t)15;
    const size_t iv4_bytes   = (size_t)CELLS_ * sizeof(int4);                   // 0.52 MB
    const size_t map_bytes   = (size_t)CELLS_ * sizeof(int);                    // 0.13 MB

    if (ws_size >= featT_bytes + pair_bytes + iv4_bytes + map_bytes &&
        n_intervals <= CELLS_) {
        __hip_bfloat16* featT = (__hip_bfloat16*)d_ws;
        unsigned int*   pair  = (unsigned int*)((char*)d_ws + featT_bytes);
        int4*           iv4   = (int4*)((char*)d_ws + featT_bytes + pair_bytes);
        int*            map   = (int*)((char*)d_ws + featT_bytes + pair_bytes + iv4_bytes);

        const int prep_blocks = TF_BLOCKS + PG_BLOCKS + IV_BLOCKS;
        prep_k<<<prep_blocks, 256, 0, stream>>>(
            feat, featT, depth, rd, rf, pair, n_points,
            istart, ilen, rb, iv4, map, n_intervals);

        bevpool_cells_k<<<(CELLS_ / CB_) * 2, 1024, 0, stream>>>(
            pair, (const uint4*)featT, iv4, map, out);
    } else {
        hipMemsetAsync(out, 0, (size_t)out_size * sizeof(float), stream);
        const int blocks = (n_intervals + 3) / 4;
        bevpool_fallback_k<<<blocks, 256, 0, stream>>>(
            depth, feat, rd, rf, rb, istart, ilen, out, n_intervals);
    }
}